// Round 1
// baseline (753.099 us; speedup 1.0000x reference)
//
#include <hip/hip_runtime.h>

// LinearAttention: out = (elu(xWq^T+bq)+1) @ [ (elu(xWk^T+bk)+1)^T (xWv^T+bv) ]_b @ Wo^T + bo
// S=4096, B=8, D=1024. All-GEMM bf16 MFMA pipeline.

typedef __bf16 bf16;
typedef __attribute__((ext_vector_type(8))) __bf16 bf16x8;
typedef __attribute__((ext_vector_type(4))) __bf16 bf16x4;
typedef __attribute__((ext_vector_type(4))) float f32x4;

static constexpr int S = 4096;
static constexpr int B = 8;
static constexpr int D = 1024;
static constexpr int SB = S * B;           // 32768 rows
static constexpr long long NELEM = (long long)SB * D;   // 33,554,432

// ---------------- fp32 -> bf16 convert ----------------
__global__ void cvt_f32_to_bf16(const float* __restrict__ in, bf16* __restrict__ out, int n)
{
    int i = (blockIdx.x * blockDim.x + threadIdx.x) * 4;
    int stride = gridDim.x * blockDim.x * 4;
    for (; i < n; i += stride) {
        float4 v = *(const float4*)(in + i);
        bf16x4 o;
        o[0] = (bf16)v.x; o[1] = (bf16)v.y; o[2] = (bf16)v.z; o[3] = (bf16)v.w;
        *(bf16x4*)(out + i) = o;
    }
}

// ---------------- (S,B,D) -> (B,D,S) transpose, bf16 ----------------
// grid: (S/64, D/64, B), 256 threads
__global__ __launch_bounds__(256) void transpose_sbd_bds(
    const bf16* __restrict__ in, bf16* __restrict__ out)
{
    __shared__ bf16 tile[64 * 72];   // tile[d][s], row stride 72 (144B, 16B-aligned)
    const int b  = blockIdx.z;
    const int s0 = blockIdx.x * 64;
    const int d0 = blockIdx.y * 64;
    const int t  = threadIdx.x;
    const int rl = t >> 3;           // 0..31
    const int c8 = (t & 7) * 8;      // 0..56

    #pragma unroll
    for (int p = 0; p < 2; ++p) {
        int r = rl + p * 32;         // s offset within tile
        bf16x8 v = *(const bf16x8*)(in + (long long)(s0 + r) * (B * D) + b * D + d0 + c8);
        #pragma unroll
        for (int j = 0; j < 8; ++j)
            tile[(c8 + j) * 72 + r] = v[j];
    }
    __syncthreads();
    #pragma unroll
    for (int p = 0; p < 2; ++p) {
        int dr = rl + p * 32;        // d offset within tile
        bf16x8 v = *(const bf16x8*)(&tile[dr * 72 + c8]);
        *(bf16x8*)(out + (long long)b * D * S + (long long)(d0 + dr) * S + s0 + c8) = v;
    }
}

// ---------------- bf16 GEMM: C = A @ B^T (+bias) (+elu+1) ----------------
// A: [M][K] row-major (row stride lda), B: [N][K] row-major (row stride ldb).
// grid: (N/128, M/128, nbatch). 256 threads = 4 waves in 2x2, each wave 64x64
// via 4x4 frags of mfma_f32_16x16x32_bf16. Single-buffered LDS, reg-staged.
// EPI: 0 = none, 1 = elu(v)+1.  OUTF32: 0 = store bf16, 1 = store fp32.
template<int EPI, int OUTF32>
__global__ __launch_bounds__(256, 2) void gemm_bt(
    const bf16* __restrict__ A, const bf16* __restrict__ Bm,
    const float* __restrict__ bias, void* __restrict__ Cout,
    int lda, int ldb, int ldc, int K,
    long long aBatch, long long bBatch, long long cBatch)
{
    __shared__ bf16 As[128 * 64];
    __shared__ bf16 Bs[128 * 64];

    const int tid  = threadIdx.x;
    const int lane = tid & 63;
    const int wave = tid >> 6;
    const int wr   = wave >> 1;      // 0..1
    const int wc   = wave & 1;       // 0..1
    const int bz   = blockIdx.z;
    const long long m0 = (long long)blockIdx.y * 128;
    const long long n0 = (long long)blockIdx.x * 128;

    const bf16* Ab = A  + bz * aBatch + m0 * lda;
    const bf16* Bb = Bm + bz * bBatch + n0 * ldb;

    f32x4 acc[4][4] = {};

    const int srow = tid >> 3;        // 0..31
    const int scol = (tid & 7) * 8;   // 0..56 (elems)

    for (int k0 = 0; k0 < K; k0 += 64) {
        #pragma unroll
        for (int i = 0; i < 4; ++i) {
            int row = srow + i * 32;
            bf16x8 va = *(const bf16x8*)(Ab + (long long)row * lda + k0 + scol);
            bf16x8 vb = *(const bf16x8*)(Bb + (long long)row * ldb + k0 + scol);
            *(bf16x8*)(&As[row * 64 + scol]) = va;
            *(bf16x8*)(&Bs[row * 64 + scol]) = vb;
        }
        __syncthreads();
        #pragma unroll
        for (int kk = 0; kk < 64; kk += 32) {
            const int ko = kk + (lane >> 4) * 8;
            bf16x8 a[4], b[4];
            #pragma unroll
            for (int mi = 0; mi < 4; ++mi)
                a[mi] = *(const bf16x8*)(&As[(wr * 64 + mi * 16 + (lane & 15)) * 64 + ko]);
            #pragma unroll
            for (int ni = 0; ni < 4; ++ni)
                b[ni] = *(const bf16x8*)(&Bs[(wc * 64 + ni * 16 + (lane & 15)) * 64 + ko]);
            #pragma unroll
            for (int mi = 0; mi < 4; ++mi)
                #pragma unroll
                for (int ni = 0; ni < 4; ++ni)
                    acc[mi][ni] = __builtin_amdgcn_mfma_f32_16x16x32_bf16(
                        a[mi], b[ni], acc[mi][ni], 0, 0, 0);
        }
        __syncthreads();
    }

    // epilogue: C/D layout col = lane&15, row = (lane>>4)*4 + j  [m89-verified]
    const int crow = (lane >> 4) * 4;
    const int ccol = lane & 15;
    #pragma unroll
    for (int ni = 0; ni < 4; ++ni) {
        const long long c = n0 + wc * 64 + ni * 16 + ccol;
        const float bv = bias ? bias[c] : 0.0f;
        #pragma unroll
        for (int mi = 0; mi < 4; ++mi) {
            const long long r0 = m0 + wr * 64 + mi * 16 + crow;
            #pragma unroll
            for (int j = 0; j < 4; ++j) {
                float v = acc[mi][ni][j] + bv;
                if (EPI == 1) v = (v > 0.0f) ? (v + 1.0f) : __expf(v);  // elu(v)+1
                const long long idx = bz * cBatch + (r0 + j) * ldc + c;
                if (OUTF32) ((float*)Cout)[idx] = v;
                else        ((bf16*)Cout)[idx]  = (bf16)v;
            }
        }
    }
}

// ---------------- launch ----------------
extern "C" void kernel_launch(void* const* d_in, const int* in_sizes, int n_in,
                              void* d_out, int out_size, void* d_ws, size_t ws_size,
                              hipStream_t stream)
{
    const float* x  = (const float*)d_in[0];
    const float* Wq = (const float*)d_in[1];
    const float* bq = (const float*)d_in[2];
    const float* Wk = (const float*)d_in[3];
    const float* bk = (const float*)d_in[4];
    const float* Wv = (const float*)d_in[5];
    const float* bv = (const float*)d_in[6];
    const float* Wo = (const float*)d_in[7];
    const float* bo = (const float*)d_in[8];
    float* out = (float*)d_out;

    // workspace layout (bytes): need 152 MiB
    //   [0,64M)    xb  -> later Kt -> later Ob   (all 64 MiB, sequentially dead)
    //   [64M,128M) Qb
    //   [128M,144M) KVT (bf16, [b][e][d])
    //   [144M,152M) wq,wk,wv,wo bf16
    char* ws = (char*)d_ws;
    if (ws_size < (size_t)159383552) return;  // cannot proceed; harness will flag
    bf16* xb  = (bf16*)(ws + 0);
    bf16* Qb  = (bf16*)(ws + 67108864);
    bf16* KVT = (bf16*)(ws + 134217728);
    bf16* wqb = (bf16*)(ws + 150994944);
    bf16* wkb = wqb + 1048576;
    bf16* wvb = wkb + 1048576;
    bf16* wob = wvb + 1048576;
    bf16* Kt  = (bf16*)(ws + 0);           // aliases xb (dead after projections)
    bf16* Ob  = (bf16*)(ws + 0);           // aliases Kt (dead after KV gemm)
    // d_out as scratch (fully overwritten by final projection):
    bf16* Kb = (bf16*)d_out;               // [0,64M)
    bf16* Vb = Kb + NELEM;                 // [64M,128M)
    bf16* Vt = (bf16*)d_out;               // aliases Kb (dead after K-transpose)

    dim3 blk(256);

    // 1) convert inputs to bf16
    cvt_f32_to_bf16<<<4096, blk, 0, stream>>>(x,  xb,  (int)NELEM);
    cvt_f32_to_bf16<<<1024, blk, 0, stream>>>(Wq, wqb, D * D);
    cvt_f32_to_bf16<<<1024, blk, 0, stream>>>(Wk, wkb, D * D);
    cvt_f32_to_bf16<<<1024, blk, 0, stream>>>(Wv, wvb, D * D);
    cvt_f32_to_bf16<<<1024, blk, 0, stream>>>(Wo, wob, D * D);

    // 2) projections: rows = (s,b) flattened, M=32768, N=1024, K=1024
    dim3 gp(D / 128, SB / 128, 1);
    gemm_bt<1, 0><<<gp, blk, 0, stream>>>(xb, wqb, bq, Qb, D, D, D, D, 0, 0, 0);
    gemm_bt<1, 0><<<gp, blk, 0, stream>>>(xb, wkb, bk, Kb, D, D, D, D, 0, 0, 0);
    gemm_bt<0, 0><<<gp, blk, 0, stream>>>(xb, wvb, bv, Vb, D, D, D, D, 0, 0, 0);

    // 3) transpose K then V to [b][d][s]  (K first: Vt overwrites Kb)
    dim3 gt(S / 64, D / 64, B);
    transpose_sbd_bds<<<gt, blk, 0, stream>>>(Kb, Kt);
    transpose_sbd_bds<<<gt, blk, 0, stream>>>(Vb, Vt);

    // 4) KVT[b][e][d] = sum_s V[s,b,e]*K[s,b,d]: A=Vt, B=Kt, M=N=1024, K=4096
    dim3 g2(D / 128, D / 128, B);
    gemm_bt<0, 0><<<g2, blk, 0, stream>>>(Vt, Kt, nullptr, KVT,
                                          S, S, D, S,
                                          (long long)D * S, (long long)D * S,
                                          (long long)D * D);

    // 5) O[s,b,e] = sum_d Q[s,b,d]*KVT[b][e][d]: batched rows, M=4096/batch
    dim3 g4(D / 128, S / 128, B);
    gemm_bt<0, 0><<<g4, blk, 0, stream>>>(Qb, KVT, nullptr, Ob,
                                          B * D, D, B * D, D,
                                          (long long)D, (long long)D * D,
                                          (long long)D);

    // 6) out = O @ Wo^T + bo (fp32 out), clobbers d_out scratch (all dead)
    gemm_bt<0, 1><<<gp, blk, 0, stream>>>(Ob, wob, bo, out, D, D, D, D, 0, 0, 0);
}

// Round 2
// 613.040 us; speedup vs baseline: 1.2285x; 1.2285x over previous
//
#include <hip/hip_runtime.h>

// LinearAttention: out = (elu(xWq^T+bq)+1) @ [ (elu(xWk^T+bk)+1)^T (xWv^T+bv) ]_b @ Wo^T + bo
// S=4096, B=8, D=1024. All-GEMM bf16 MFMA pipeline, m97-style global_load_lds staging.
// K/V are produced directly in [b][d][s] layout (weight-as-A GEMM) -> no transpose passes.

typedef __bf16 bf16;
typedef __attribute__((ext_vector_type(8))) __bf16 bf16x8;
typedef __attribute__((ext_vector_type(4))) __bf16 bf16x4;
typedef __attribute__((ext_vector_type(4))) float f32x4;

static constexpr int S = 4096;
static constexpr int B = 8;
static constexpr int D = 1024;
static constexpr int SB = S * B;                       // 32768
static constexpr long long NELEM = (long long)SB * D;  // 33,554,432

__device__ __forceinline__ void load_lds16(const bf16* g, bf16* l)
{
    __builtin_amdgcn_global_load_lds(
        (const __attribute__((address_space(1))) void*)g,
        (__attribute__((address_space(3))) void*)l, 16, 0, 0);
}

// ---------------- fp32 -> bf16 convert ----------------
__global__ void cvt_f32_to_bf16(const float* __restrict__ in, bf16* __restrict__ out, int n)
{
    int i = (blockIdx.x * blockDim.x + threadIdx.x) * 4;
    int stride = gridDim.x * blockDim.x * 4;
    for (; i < n; i += stride) {
        float4 v = *(const float4*)(in + i);
        bf16x4 o;
        o[0] = (bf16)v.x; o[1] = (bf16)v.y; o[2] = (bf16)v.z; o[3] = (bf16)v.w;
        *(bf16x4*)(out + i) = o;
    }
}

// ---------------- bf16 GEMM: C = A @ B^T (+bias) (+elu+1) ----------------
// A: [M][K] row-major (row stride lda), B: [N][K] row-major (row stride ldb).
// grid: (N/128, M/128, nbatch), 256 thr = 4 waves 2x2, wave = 64x64 via 4x4
// frags of mfma_f32_16x16x32_bf16. Staging: global_load_lds dwordx4 (m97).
// XCD swizzle on flat (x,y) id — requires gridDim.x*gridDim.y % 8 == 0.
// EPI: 1 = elu(v)+1.  OUTF32: 1 = fp32 store.  BIASROW: bias indexed by row.
template<int EPI, int OUTF32, int BIASROW>
__global__ __launch_bounds__(256, 2) void gemm_bt(
    const bf16* __restrict__ A, const bf16* __restrict__ Bm,
    const float* __restrict__ bias, void* __restrict__ Cout,
    int lda, int ldb, int ldc, int K,
    long long aBatch, long long bBatch, long long cBatch)
{
    __shared__ bf16 As[128 * 64];
    __shared__ bf16 Bs[128 * 64];

    const int tid  = threadIdx.x;
    const int lane = tid & 63;
    const int wave = tid >> 6;
    const int wr   = wave >> 1;
    const int wc   = wave & 1;
    const int bz   = blockIdx.z;

    // XCD-aware swizzle (bijective: nxy % 8 == 0 for all launches here)
    const int nx  = gridDim.x;
    const int bid = blockIdx.y * nx + blockIdx.x;
    const int cpx = (nx * gridDim.y) >> 3;
    const int swz = (bid & 7) * cpx + (bid >> 3);
    const long long m0 = (long long)(swz / nx) * 128;
    const long long n0 = (long long)(swz % nx) * 128;

    const bf16* Ab = A  + bz * aBatch + m0 * lda;
    const bf16* Bb = Bm + bz * bBatch + n0 * ldb;

    f32x4 acc[4][4] = {};

    const int lrow = lane >> 3;        // 0..7
    const int lcol = (lane & 7) * 8;   // 0..56 elems (16B granules)

    for (int k0 = 0; k0 < K; k0 += 64) {
        #pragma unroll
        for (int i = 0; i < 4; ++i) {
            const int rbase = i * 32 + wave * 8;      // wave-uniform row base
            load_lds16(Ab + (long long)(rbase + lrow) * lda + k0 + lcol, &As[rbase * 64]);
            load_lds16(Bb + (long long)(rbase + lrow) * ldb + k0 + lcol, &Bs[rbase * 64]);
        }
        __syncthreads();               // compiler emits vmcnt(0) drain here
        #pragma unroll
        for (int kk = 0; kk < 64; kk += 32) {
            const int ko = kk + (lane >> 4) * 8;
            bf16x8 a[4], b[4];
            #pragma unroll
            for (int mi = 0; mi < 4; ++mi)
                a[mi] = *(const bf16x8*)(&As[(wr * 64 + mi * 16 + (lane & 15)) * 64 + ko]);
            #pragma unroll
            for (int ni = 0; ni < 4; ++ni)
                b[ni] = *(const bf16x8*)(&Bs[(wc * 64 + ni * 16 + (lane & 15)) * 64 + ko]);
            #pragma unroll
            for (int mi = 0; mi < 4; ++mi)
                #pragma unroll
                for (int ni = 0; ni < 4; ++ni)
                    acc[mi][ni] = __builtin_amdgcn_mfma_f32_16x16x32_bf16(
                        a[mi], b[ni], acc[mi][ni], 0, 0, 0);
        }
        __syncthreads();
    }

    // epilogue: C/D layout col = lane&15, row = (lane>>4)*4 + j  [m89-verified]
    const int crow = (lane >> 4) * 4;
    const int ccol = lane & 15;
    #pragma unroll
    for (int ni = 0; ni < 4; ++ni) {
        const long long c = n0 + wc * 64 + ni * 16 + ccol;
        float bcol = 0.0f;
        if (!BIASROW && bias) bcol = bias[c];
        #pragma unroll
        for (int mi = 0; mi < 4; ++mi) {
            const long long r0 = m0 + wr * 64 + mi * 16 + crow;
            #pragma unroll
            for (int j = 0; j < 4; ++j) {
                float v = acc[mi][ni][j];
                v += BIASROW ? bias[r0 + j] : bcol;
                if (EPI == 1) v = (v > 0.0f) ? (v + 1.0f) : __expf(v);  // elu(v)+1
                const long long idx = bz * cBatch + (r0 + j) * ldc + c;
                if (OUTF32) ((float*)Cout)[idx] = v;
                else        ((bf16*)Cout)[idx]  = (bf16)v;
            }
        }
    }
}

// ---------------- launch ----------------
extern "C" void kernel_launch(void* const* d_in, const int* in_sizes, int n_in,
                              void* d_out, int out_size, void* d_ws, size_t ws_size,
                              hipStream_t stream)
{
    const float* x  = (const float*)d_in[0];
    const float* Wq = (const float*)d_in[1];
    const float* bq = (const float*)d_in[2];
    const float* Wk = (const float*)d_in[3];
    const float* bk = (const float*)d_in[4];
    const float* Wv = (const float*)d_in[5];
    const float* bv = (const float*)d_in[6];
    const float* Wo = (const float*)d_in[7];
    const float* bo = (const float*)d_in[8];
    float* out = (float*)d_out;

    // ws layout:  [0,64M) xb -> Ob (xb dead after Vt/Kt/Q gemms; Ob written later)
    //             [64M,128M) Qb   [128M,144M) KVT   [144M,152M) bf16 weights
    // d_out (128 MiB) as scratch: Kt [0,64M), Vt [64M,128M) — dead before final write.
    char* ws = (char*)d_ws;
    if (ws_size < (size_t)159383552) return;
    bf16* xb  = (bf16*)(ws + 0);
    bf16* Qb  = (bf16*)(ws + 67108864);
    bf16* KVT = (bf16*)(ws + 134217728);
    bf16* wqb = (bf16*)(ws + 150994944);
    bf16* wkb = wqb + 1048576;
    bf16* wvb = wkb + 1048576;
    bf16* wob = wvb + 1048576;
    bf16* Ob  = (bf16*)(ws + 0);       // aliases xb
    bf16* Kt  = (bf16*)d_out;          // [b][d][s]
    bf16* Vt  = Kt + NELEM;            // [b][e][s]

    dim3 blk(256);

    // 1) converts
    cvt_f32_to_bf16<<<4096, blk, 0, stream>>>(x,  xb,  (int)NELEM);
    cvt_f32_to_bf16<<<1024, blk, 0, stream>>>(Wq, wqb, D * D);
    cvt_f32_to_bf16<<<1024, blk, 0, stream>>>(Wk, wkb, D * D);
    cvt_f32_to_bf16<<<1024, blk, 0, stream>>>(Wv, wvb, D * D);
    cvt_f32_to_bf16<<<1024, blk, 0, stream>>>(Wo, wob, D * D);

    // 2) Q projection: [(s,b)][d] rows, M=32768, N=1024, K=1024
    dim3 gpQ(D / 128, SB / 128, 1);
    gemm_bt<1, 0, 0><<<gpQ, blk, 0, stream>>>(xb, wqb, bq, Qb, D, D, D, D, 0, 0, 0);

    // 3) Kt[b][d][s] = elu(Wk @ x_b^T + bk)+1 : A=Wk (M=d), B=x_b (N=s), bias by row
    dim3 gKV(S / 128, D / 128, B);
    gemm_bt<1, 0, 1><<<gKV, blk, 0, stream>>>(wkb, xb, bk, Kt,
                                              D, B * D, S, D,
                                              0, (long long)D, (long long)D * S);
    // 4) Vt[b][e][s] = Wv @ x_b^T + bv
    gemm_bt<0, 0, 1><<<gKV, blk, 0, stream>>>(wvb, xb, bv, Vt,
                                              D, B * D, S, D,
                                              0, (long long)D, (long long)D * S);

    // 5) KVT[b][e][d] = sum_s Vt[b][e][s] * Kt[b][d][s]  (M=N=1024, K=4096)
    dim3 g2(D / 128, D / 128, B);
    gemm_bt<0, 0, 0><<<g2, blk, 0, stream>>>(Vt, Kt, nullptr, KVT,
                                             S, S, D, S,
                                             (long long)D * S, (long long)D * S,
                                             (long long)D * D);

    // 6) Ob[s,b,e] = sum_d Q[s,b,d] * KVT[b][e][d]  (per-batch M=4096)
    dim3 g4(D / 128, S / 128, B);
    gemm_bt<0, 0, 0><<<g4, blk, 0, stream>>>(Qb, KVT, nullptr, Ob,
                                             B * D, D, B * D, D,
                                             (long long)D, (long long)D * D,
                                             (long long)D);

    // 7) out = Ob @ Wo^T + bo (fp32), fully overwrites d_out scratch
    gemm_bt<0, 1, 0><<<gpQ, blk, 0, stream>>>(Ob, wob, bo, out, D, D, D, D, 0, 0, 0);
}

// Round 3
// 523.676 us; speedup vs baseline: 1.4381x; 1.1706x over previous
//
#include <hip/hip_runtime.h>

// LinearAttention, S=4096 B=8 D=1024.
// out = Q @ (Wo @ (K^T V)_b)^T + bo,  Q=elu(xWq^T+bq)+1, K=elu(xWk^T+bk)+1, V=xWv^T+bv
// bf16 MFMA GEMM with 4-deep LDS ring, counted vmcnt, T2 swizzle, T1 XCD swizzle, T5 setprio.

typedef __bf16 bf16;
typedef __attribute__((ext_vector_type(8))) __bf16 bf16x8;
typedef __attribute__((ext_vector_type(4))) __bf16 bf16x4;
typedef __attribute__((ext_vector_type(4))) float f32x4;

static constexpr int S = 4096;
static constexpr int B = 8;
static constexpr int D = 1024;
static constexpr int SB = S * B;
static constexpr long long NELEM = (long long)SB * D;

__device__ __forceinline__ void load_lds16(const bf16* g, void* l)
{
    __builtin_amdgcn_global_load_lds(
        (const __attribute__((address_space(1))) void*)g,
        (__attribute__((address_space(3))) void*)l, 16, 0, 0);
}

// ---------------- fp32 -> bf16 convert ----------------
__global__ void cvt_f32_to_bf16(const float* __restrict__ in, bf16* __restrict__ out, int n)
{
    int i = (blockIdx.x * blockDim.x + threadIdx.x) * 4;
    int stride = gridDim.x * blockDim.x * 4;
    for (; i < n; i += stride) {
        float4 v = *(const float4*)(in + i);
        bf16x4 o;
        o[0] = (bf16)v.x; o[1] = (bf16)v.y; o[2] = (bf16)v.z; o[3] = (bf16)v.w;
        *(bf16x4*)(out + i) = o;
    }
}

// ---------------- pipelined bf16 GEMM: C = A @ B^T ----------------
// A:[M][K] lda, B:[N][K] ldb, C:[M][N] ldc. BK=32, 4-buffer LDS ring.
// Waves: WM x WN grid, per-wave (BM/WM)x(BN/WN) output.
// LDS layout per buffer: A-part [BM][32] bf16 then B-part [BN][32], each with
// T2 swizzle: byte ^= ((byte>>7)&3)<<4  (row bits 1-2 XOR into 16B-granule idx).
// Staged via global_load_lds (linear dest) with inverse-swizzled global source.
template<int BM, int BN, int WM, int WN, int EPI, int OUTF32, int BIASROW>
__global__ __launch_bounds__(WM * WN * 64, 2) void gemm_bt(
    const bf16* __restrict__ A, const bf16* __restrict__ Bm,
    const float* __restrict__ bias, void* __restrict__ Cout,
    int lda, int ldb, int ldc, int K,
    long long aBatch, long long bBatch, long long cBatch)
{
    constexpr int THREADS = WM * WN * 64;
    constexpr int WROWS = BM / WM, WCOLS = BN / WN;
    constexpr int MI = WROWS / 16, NI = WCOLS / 16;
    constexpr int ABYTES = BM * 64;           // BM rows x 32 bf16
    constexpr int BBYTES = BN * 64;
    constexpr int BUF = ABYTES + BBYTES;

    __shared__ unsigned char smem[4 * BUF];

    const int tid  = threadIdx.x;
    const int lane = tid & 63;
    const int wave = tid >> 6;
    const int wr   = wave / WN;
    const int wc   = wave % WN;
    const int bz   = blockIdx.z;

    // T1: XCD-aware swizzle on flat (x,y) id; all grids have nx*ny % 8 == 0
    const int nx  = gridDim.x;
    const int bid = blockIdx.y * nx + blockIdx.x;
    const int cpx = (nx * gridDim.y) >> 3;
    const int swz = (bid & 7) * cpx + (bid >> 3);
    const long long m0 = (long long)(swz / nx) * BM;
    const long long n0 = (long long)(swz % nx) * BN;

    const bf16* Ab = A  + bz * aBatch + m0 * lda;
    const bf16* Bb = Bm + bz * bBatch + n0 * ldb;

    f32x4 acc[MI][NI] = {};

    const int NT = K >> 5;   // K/32 tiles

    // stage K-tile t into ring buffer (t&3). Per thread: 2 A + 2 B gload_lds.
    auto stage = [&](int t) {
        unsigned char* dst = smem + (t & 3) * BUF;
        const long long kk = (long long)t << 5;
        #pragma unroll
        for (int j = 0; j < 2; ++j) {
            const int g  = wave * 64 + lane + j * THREADS;     // linear granule
            const int gs = g ^ ((g >> 3) & 3);                 // inverse swizzle (involution)
            const int row = gs >> 2, col = (gs & 3) * 8;
            load_lds16(Ab + (long long)row * lda + kk + col,
                       dst + (wave * 64 + j * THREADS) * 16);  // wave-uniform base
        }
        #pragma unroll
        for (int j = 0; j < 2; ++j) {
            const int g  = wave * 64 + lane + j * THREADS;
            const int gs = g ^ ((g >> 3) & 3);
            const int row = gs >> 2, col = (gs & 3) * 8;
            load_lds16(Bb + (long long)row * ldb + kk + col,
                       dst + ABYTES + (wave * 64 + j * THREADS) * 16);
        }
    };

    stage(0); stage(1); stage(2);   // 12 issues/thread in flight

    const int ko2 = (lane >> 4) * 16;   // byte offset of this lane's k-slot
    const int la15 = lane & 15;

    for (int t = 0; t < NT; ++t) {
        // counted waits: ensure stage(t) landed; keep newer stages in flight
        if (t + 2 < NT)      asm volatile("s_waitcnt vmcnt(8)" ::: "memory");
        else if (t + 1 < NT) asm volatile("s_waitcnt vmcnt(4)" ::: "memory");
        else                 asm volatile("s_waitcnt vmcnt(0)" ::: "memory");
        __builtin_amdgcn_s_barrier();
        asm volatile("" ::: "memory");   // pin LDS reads below the barrier

        if (t + 3 < NT) stage(t + 3);

        const unsigned char* buf = smem + (t & 3) * BUF;
        bf16x8 a[MI], b[NI];
        #pragma unroll
        for (int mi = 0; mi < MI; ++mi) {
            int ad = (wr * WROWS + mi * 16 + la15) * 64 + ko2;
            ad ^= ((ad >> 7) & 3) << 4;                        // T2 swizzle
            a[mi] = *(const bf16x8*)(buf + ad);
        }
        #pragma unroll
        for (int ni = 0; ni < NI; ++ni) {
            int ad = (wc * WCOLS + ni * 16 + la15) * 64 + ko2;
            ad ^= ((ad >> 7) & 3) << 4;
            b[ni] = *(const bf16x8*)(buf + ABYTES + ad);
        }

        __builtin_amdgcn_s_setprio(1);
        #pragma unroll
        for (int mi = 0; mi < MI; ++mi)
            #pragma unroll
            for (int ni = 0; ni < NI; ++ni)
                acc[mi][ni] = __builtin_amdgcn_mfma_f32_16x16x32_bf16(
                    a[mi], b[ni], acc[mi][ni], 0, 0, 0);
        __builtin_amdgcn_s_setprio(0);
    }

    // epilogue: C/D layout col = lane&15, row = (lane>>4)*4 + j
    const int crow = (lane >> 4) * 4;
    const int ccol = lane & 15;
    #pragma unroll
    for (int ni = 0; ni < NI; ++ni) {
        const long long c = n0 + wc * WCOLS + ni * 16 + ccol;
        float bcol = 0.0f;
        if (!BIASROW && bias) bcol = bias[c];
        #pragma unroll
        for (int mi = 0; mi < MI; ++mi) {
            const long long r0 = m0 + wr * WROWS + mi * 16 + crow;
            #pragma unroll
            for (int j = 0; j < 4; ++j) {
                float v = acc[mi][ni][j];
                v += BIASROW ? bias[r0 + j] : bcol;
                if (EPI == 1) v = (v > 0.0f) ? (v + 1.0f) : __expf(v);   // elu+1
                const long long idx = bz * cBatch + (r0 + j) * ldc + c;
                if (OUTF32) ((float*)Cout)[idx] = v;
                else        ((bf16*)Cout)[idx]  = (bf16)v;
            }
        }
    }
}

// ---------------- launch ----------------
extern "C" void kernel_launch(void* const* d_in, const int* in_sizes, int n_in,
                              void* d_out, int out_size, void* d_ws, size_t ws_size,
                              hipStream_t stream)
{
    const float* x  = (const float*)d_in[0];
    const float* Wq = (const float*)d_in[1];
    const float* bq = (const float*)d_in[2];
    const float* Wk = (const float*)d_in[3];
    const float* bk = (const float*)d_in[4];
    const float* Wv = (const float*)d_in[5];
    const float* bv = (const float*)d_in[6];
    const float* Wo = (const float*)d_in[7];
    const float* bo = (const float*)d_in[8];
    float* out = (float*)d_out;

    // ws: [0,64M) xb -> KVWT (xb dead after Q/Kt/Vt gemms)
    //     [64M,128M) Qb   [128M,144M) KV   [144M,152M) bf16 weights
    // d_out scratch: Kt [0,64M), Vt [64M,128M) — dead before final write.
    char* ws = (char*)d_ws;
    if (ws_size < (size_t)159383552) return;
    bf16* xb   = (bf16*)(ws + 0);
    bf16* KVWT = (bf16*)(ws + 0);          // aliases xb (dead)
    bf16* Qb   = (bf16*)(ws + 67108864);
    bf16* KV   = (bf16*)(ws + 134217728);
    bf16* wqb  = (bf16*)(ws + 150994944);
    bf16* wkb  = wqb + 1048576;
    bf16* wvb  = wkb + 1048576;
    bf16* wob  = wvb + 1048576;
    bf16* Kt   = (bf16*)d_out;             // [b][d][s]
    bf16* Vt   = Kt + NELEM;               // [b][e][s]

    // 1) converts
    cvt_f32_to_bf16<<<4096, 256, 0, stream>>>(x,  xb,  (int)NELEM);
    cvt_f32_to_bf16<<<1024, 256, 0, stream>>>(Wq, wqb, D * D);
    cvt_f32_to_bf16<<<1024, 256, 0, stream>>>(Wk, wkb, D * D);
    cvt_f32_to_bf16<<<1024, 256, 0, stream>>>(Wv, wvb, D * D);
    cvt_f32_to_bf16<<<1024, 256, 0, stream>>>(Wo, wob, D * D);

    // 2) Qb[(s,b)][d] = elu(x Wq^T + bq)+1 : M=32768 N=1024 K=1024
    gemm_bt<256, 256, 2, 4, 1, 0, 0><<<dim3(4, 128, 1), 512, 0, stream>>>(
        xb, wqb, bq, Qb, D, D, D, D, 0, 0, 0);

    // 3) Kt[b][d][s] = elu(Wk x_b^T + bk)+1 : A=Wk (M=d), B=x_b (N=s), row bias
    gemm_bt<256, 256, 2, 4, 1, 0, 1><<<dim3(16, 4, 8), 512, 0, stream>>>(
        wkb, xb, bk, Kt, D, B * D, S, D, 0, (long long)D, (long long)D * S);

    // 4) Vt[b][e][s] = Wv x_b^T + bv
    gemm_bt<256, 256, 2, 4, 0, 0, 1><<<dim3(16, 4, 8), 512, 0, stream>>>(
        wvb, xb, bv, Vt, D, B * D, S, D, 0, (long long)D, (long long)D * S);

    // 5) KV[b][d][e] = sum_s Kt[b][d][s] Vt[b][e][s] : M=N=1024, K=4096
    gemm_bt<128, 128, 2, 2, 0, 0, 0><<<dim3(8, 8, 8), 256, 0, stream>>>(
        Kt, Vt, nullptr, KV, S, S, D, S,
        (long long)D * S, (long long)D * S, (long long)D * D);

    // 6) KVWT[b][e'][d] = sum_e Wo[e'][e] KV[b][d][e] : M=N=1024, K=1024
    gemm_bt<128, 128, 2, 2, 0, 0, 0><<<dim3(8, 8, 8), 256, 0, stream>>>(
        wob, KV, nullptr, KVWT, D, D, D, D,
        0, (long long)D * D, (long long)D * D);

    // 7) out[s,b,e'] = sum_d Qb[(s,b)][d] KVWT[b][e'][d] + bo  (fp32 out)
    gemm_bt<256, 256, 2, 4, 0, 1, 0><<<dim3(4, 16, 8), 512, 0, stream>>>(
        Qb, KVWT, bo, out, B * D, D, B * D, D,
        (long long)D, (long long)D * D, (long long)D);
}

// Round 4
// 509.811 us; speedup vs baseline: 1.4772x; 1.0272x over previous
//
#include <hip/hip_runtime.h>

// LinearAttention, S=4096 B=8 D=1024.
// out = Q @ (K^T V')_b^T + bo with V' = x Wvo^T + bvo, Wvo = Wo Wv, bvo = Wo bv
// (Wo folded into V-projection; KVWT GEMM eliminated).
// Big GEMMs: 256^2 8-phase schedule (T2 swizzle + counted vmcnt + setprio).

typedef __bf16 bf16;
typedef __attribute__((ext_vector_type(8))) __bf16 bf16x8;
typedef __attribute__((ext_vector_type(4))) __bf16 bf16x4;
typedef __attribute__((ext_vector_type(4))) float f32x4;

static constexpr int S = 4096;
static constexpr int B = 8;
static constexpr int D = 1024;
static constexpr int SB = S * B;
static constexpr long long NELEM = (long long)SB * D;

__device__ __forceinline__ void load_lds16(const bf16* g, void* l)
{
    __builtin_amdgcn_global_load_lds(
        (const __attribute__((address_space(1))) void*)g,
        (__attribute__((address_space(3))) void*)l, 16, 0, 0);
}

// ---------------- fp32 -> bf16 convert ----------------
__global__ void cvt_f32_to_bf16(const float* __restrict__ in, bf16* __restrict__ out, int n)
{
    int i = (blockIdx.x * blockDim.x + threadIdx.x) * 4;
    int stride = gridDim.x * blockDim.x * 4;
    for (; i < n; i += stride) {
        float4 v = *(const float4*)(in + i);
        bf16x4 o;
        o[0] = (bf16)v.x; o[1] = (bf16)v.y; o[2] = (bf16)v.z; o[3] = (bf16)v.w;
        *(bf16x4*)(out + i) = o;
    }
}

// ---------------- Wv (fp32 [e][d]) -> WvT (bf16 [d][e]) ----------------
__global__ __launch_bounds__(256) void cvt_transpose_1024(
    const float* __restrict__ in, bf16* __restrict__ out)
{
    __shared__ bf16 tile[64][72];
    const int e0 = blockIdx.y * 64;
    const int d0 = blockIdx.x * 64;
    const int t  = threadIdx.x;
    const int rl = t >> 3;
    const int c8 = (t & 7) * 8;
    #pragma unroll
    for (int p = 0; p < 2; ++p) {
        int r = rl + p * 32;
        float4 v0 = *(const float4*)(in + (long long)(e0 + r) * D + d0 + c8);
        float4 v1 = *(const float4*)(in + (long long)(e0 + r) * D + d0 + c8 + 4);
        tile[c8+0][r] = (bf16)v0.x; tile[c8+1][r] = (bf16)v0.y;
        tile[c8+2][r] = (bf16)v0.z; tile[c8+3][r] = (bf16)v0.w;
        tile[c8+4][r] = (bf16)v1.x; tile[c8+5][r] = (bf16)v1.y;
        tile[c8+6][r] = (bf16)v1.z; tile[c8+7][r] = (bf16)v1.w;
    }
    __syncthreads();
    #pragma unroll
    for (int p = 0; p < 2; ++p) {
        int dr = rl + p * 32;
        *(bf16x8*)(out + (long long)(d0 + dr) * D + e0 + c8) = *(bf16x8*)(&tile[dr][c8]);
    }
}

// ---------------- bvo = Wo @ bv (fp32) ----------------
__global__ __launch_bounds__(256) void bvo_kernel(
    const float* __restrict__ Wo, const float* __restrict__ bv, float* __restrict__ bvo)
{
    const int row = blockIdx.x;
    const int t = threadIdx.x;
    float4 w = *(const float4*)(Wo + (long long)row * D + t * 4);
    float4 b = *(const float4*)(bv + t * 4);
    float s = w.x*b.x + w.y*b.y + w.z*b.z + w.w*b.w;
    __shared__ float red[256];
    red[t] = s; __syncthreads();
    for (int off = 128; off > 0; off >>= 1) {
        if (t < off) red[t] += red[t + off];
        __syncthreads();
    }
    if (t == 0) bvo[row] = red[0];
}

// ---------------- R3 ring GEMM (verified) — used for Wvo + KVo ----------------
template<int BM, int BN, int WM, int WN, int EPI, int OUTF32, int BIASROW>
__global__ __launch_bounds__(WM * WN * 64, 2) void gemm_bt(
    const bf16* __restrict__ A, const bf16* __restrict__ Bm,
    const float* __restrict__ bias, void* __restrict__ Cout,
    int lda, int ldb, int ldc, int K,
    long long aBatch, long long bBatch, long long cBatch)
{
    constexpr int THREADS = WM * WN * 64;
    constexpr int WROWS = BM / WM, WCOLS = BN / WN;
    constexpr int MI = WROWS / 16, NI = WCOLS / 16;
    constexpr int ABYTES = BM * 64;
    constexpr int BBYTES = BN * 64;
    constexpr int BUF = ABYTES + BBYTES;

    __shared__ unsigned char smem[4 * BUF];

    const int tid  = threadIdx.x;
    const int lane = tid & 63;
    const int wave = tid >> 6;
    const int wr   = wave / WN;
    const int wc   = wave % WN;
    const int bz   = blockIdx.z;

    const int nx  = gridDim.x;
    const int bid = blockIdx.y * nx + blockIdx.x;
    const int cpx = (nx * gridDim.y) >> 3;
    const int swz = (bid & 7) * cpx + (bid >> 3);
    const long long m0 = (long long)(swz / nx) * BM;
    const long long n0 = (long long)(swz % nx) * BN;

    const bf16* Ab = A  + bz * aBatch + m0 * lda;
    const bf16* Bb = Bm + bz * bBatch + n0 * ldb;

    f32x4 acc[MI][NI] = {};
    const int NT = K >> 5;

    auto stage = [&](int t) {
        unsigned char* dst = smem + (t & 3) * BUF;
        const long long kk = (long long)t << 5;
        #pragma unroll
        for (int j = 0; j < 2; ++j) {
            const int g  = wave * 64 + lane + j * THREADS;
            const int gs = g ^ ((g >> 3) & 3);
            const int row = gs >> 2, col = (gs & 3) * 8;
            load_lds16(Ab + (long long)row * lda + kk + col,
                       dst + (wave * 64 + j * THREADS) * 16);
        }
        #pragma unroll
        for (int j = 0; j < 2; ++j) {
            const int g  = wave * 64 + lane + j * THREADS;
            const int gs = g ^ ((g >> 3) & 3);
            const int row = gs >> 2, col = (gs & 3) * 8;
            load_lds16(Bb + (long long)row * ldb + kk + col,
                       dst + ABYTES + (wave * 64 + j * THREADS) * 16);
        }
    };

    stage(0); stage(1); stage(2);

    const int ko2 = (lane >> 4) * 16;
    const int la15 = lane & 15;

    for (int t = 0; t < NT; ++t) {
        if (t + 2 < NT)      asm volatile("s_waitcnt vmcnt(8)" ::: "memory");
        else if (t + 1 < NT) asm volatile("s_waitcnt vmcnt(4)" ::: "memory");
        else                 asm volatile("s_waitcnt vmcnt(0)" ::: "memory");
        __builtin_amdgcn_s_barrier();
        asm volatile("" ::: "memory");

        if (t + 3 < NT) stage(t + 3);

        const unsigned char* buf = smem + (t & 3) * BUF;
        bf16x8 a[MI], b[NI];
        #pragma unroll
        for (int mi = 0; mi < MI; ++mi) {
            int ad = (wr * WROWS + mi * 16 + la15) * 64 + ko2;
            ad ^= ((ad >> 7) & 3) << 4;
            a[mi] = *(const bf16x8*)(buf + ad);
        }
        #pragma unroll
        for (int ni = 0; ni < NI; ++ni) {
            int ad = (wc * WCOLS + ni * 16 + la15) * 64 + ko2;
            ad ^= ((ad >> 7) & 3) << 4;
            b[ni] = *(const bf16x8*)(buf + ABYTES + ad);
        }

        __builtin_amdgcn_s_setprio(1);
        #pragma unroll
        for (int mi = 0; mi < MI; ++mi)
            #pragma unroll
            for (int ni = 0; ni < NI; ++ni)
                acc[mi][ni] = __builtin_amdgcn_mfma_f32_16x16x32_bf16(
                    a[mi], b[ni], acc[mi][ni], 0, 0, 0);
        __builtin_amdgcn_s_setprio(0);
    }

    const int crow = (lane >> 4) * 4;
    const int ccol = lane & 15;
    #pragma unroll
    for (int ni = 0; ni < NI; ++ni) {
        const long long c = n0 + wc * WCOLS + ni * 16 + ccol;
        float bcol = 0.0f;
        if (!BIASROW && bias) bcol = bias[c];
        #pragma unroll
        for (int mi = 0; mi < MI; ++mi) {
            const long long r0 = m0 + wr * WROWS + mi * 16 + crow;
            #pragma unroll
            for (int j = 0; j < 4; ++j) {
                float v = acc[mi][ni][j];
                v += BIASROW ? bias[r0 + j] : bcol;
                if (EPI == 1) v = (v > 0.0f) ? (v + 1.0f) : __expf(v);
                const long long idx = bz * cBatch + (r0 + j) * ldc + c;
                if (OUTF32) ((float*)Cout)[idx] = v;
                else        ((bf16*)Cout)[idx]  = (bf16)v;
            }
        }
    }
}

// ---------------- 256^2 8-phase GEMM: C = A @ B^T ----------------
// BM=BN=256, BK=64, 512 thr = 8 waves (2M x 4N), per-wave 128x64 output.
// LDS: [A|B] x [buf(2)] x [khalf(2)] x 16KB regions, T2-swizzled (2-way free).
// Stage slot schedule (per iter i, t=2i): P0:t+1.Akhi P1-4:t+2.{Bklo,Aklo,Bkhi,Akhi}
// P5-7:t+3.{Bklo,Aklo,Bkhi}. Gates vmcnt(10) at odd phases (8/4/0 on last iter).
template<int EPI, int OUTF32, int BIASROW>
__global__ __launch_bounds__(512, 1) void gemm8p(
    const bf16* __restrict__ A, const bf16* __restrict__ Bm,
    const float* __restrict__ bias, void* __restrict__ Cout,
    int lda, int ldb, int ldc, int K,
    long long aBatch, long long bBatch, long long cBatch)
{
    __shared__ unsigned char smem[131072];

    const int tid  = threadIdx.x;
    const int lane = tid & 63;
    const int wave = tid >> 6;
    const int wr   = wave >> 2;        // 0..1
    const int wc   = wave & 3;         // 0..3
    const int bz   = blockIdx.z;

    const int nx  = gridDim.x;
    const int bid = blockIdx.y * nx + blockIdx.x;
    const int cpx = (nx * gridDim.y) >> 3;
    const int swzb = (bid & 7) * cpx + (bid >> 3);
    const long long m0 = (long long)(swzb / nx) * 256;
    const long long n0 = (long long)(swzb % nx) * 256;

    const bf16* Ab = A  + bz * aBatch + m0 * lda;
    const bf16* Bb = Bm + bz * bBatch + n0 * ldb;

    // staging bases: granule G = wave*128 + j*64 + lane; r=G>>2; g=(lane&3)^((lane>>3)&3)
    const int sg = (lane & 3) ^ ((lane >> 3) & 3);
    const long long srow = wave * 32 + (lane >> 2);
    const bf16* srcA = Ab + srow * lda + sg * 8;
    const bf16* srcB = Bb + srow * ldb + sg * 8;
    const int dstoff = wave * 2048;    // bytes within region (+ j*1024)

    // ds_read bases (granule index within 16KB region)
    const int la15 = lane & 15;
    const int rsw  = (lane >> 4) ^ ((la15 >> 1) & 3);
    const int a16  = (wr * 128 + la15) * 4 + rsw;   // + mi*64
    const int b16  = (wc * 64  + la15) * 4 + rsw;   // + ni*64

    f32x4 acc[8][4] = {};
    const int NT = K >> 6;
    const int NI = NT >> 1;

    auto stageA = [&](int T, int kh) {
        const int reg = ((((T & 1) << 1) | kh) << 14);
        const long long kp = ((long long)T << 6) + (kh << 5);
        load_lds16(srcA + kp,            smem + reg + dstoff);
        load_lds16(srcA + kp + 16 * lda, smem + reg + dstoff + 1024);
    };
    auto stageB = [&](int T, int kh) {
        const int reg = 65536 + ((((T & 1) << 1) | kh) << 14);
        const long long kp = ((long long)T << 6) + (kh << 5);
        load_lds16(srcB + kp,            smem + reg + dstoff);
        load_lds16(srcB + kp + 16 * ldb, smem + reg + dstoff + 1024);
    };

    // prologue: t0 fully + t1 {Bklo,Aklo,Bkhi}; t1.Akhi goes in iter-0 P0 slot
    stageB(0, 0); stageA(0, 0); stageB(0, 1); stageA(0, 1);
    stageB(1, 0); stageA(1, 0); stageB(1, 1);
    asm volatile("s_waitcnt vmcnt(10)" ::: "memory");   // t0.klo landed
    __builtin_amdgcn_s_barrier();
    __builtin_amdgcn_sched_barrier(0);

    bf16x8 bfr[4];
    for (int i = 0; i < NI; ++i) {
        const int t = 2 * i;
        const bool nl = (i + 1 < NI);
        #pragma unroll
        for (int p = 0; p < 8; ++p) {
            const int ks  = (p >> 1) & 1;
            const int ch  = p & 1;
            const int buf = p >> 2;
            const int regA = ((buf << 1) | ks) << 14;
            const int regB = 65536 + regA;

            // 1. ds_reads (B only on even sub-phase; reused on odd)
            bf16x8 afr[4];
            if (ch == 0) {
                #pragma unroll
                for (int ni = 0; ni < 4; ++ni)
                    bfr[ni] = *(const bf16x8*)(smem + regB + (b16 + ni * 64) * 16);
            }
            #pragma unroll
            for (int m4 = 0; m4 < 4; ++m4)
                afr[m4] = *(const bf16x8*)(smem + regA + (a16 + (ch * 4 + m4) * 64) * 16);

            // 2. stage slot
            if      (p == 0) stageA(t + 1, 1);
            else if (p == 1) { if (t + 2 < NT) stageB(t + 2, 0); }
            else if (p == 2) { if (t + 2 < NT) stageA(t + 2, 0); }
            else if (p == 3) { if (t + 2 < NT) stageB(t + 2, 1); }
            else if (p == 4) { if (t + 2 < NT) stageA(t + 2, 1); }
            else if (p == 5) { if (t + 3 < NT) stageB(t + 3, 0); }
            else if (p == 6) { if (t + 3 < NT) stageA(t + 3, 0); }
            else             { if (t + 3 < NT) stageB(t + 3, 1); }

            // 3. counted gates (odd phases); last-iter reduced counts
            if (p == 1) {
                if (nl) asm volatile("s_waitcnt vmcnt(10)" ::: "memory");
                else    asm volatile("s_waitcnt vmcnt(8)"  ::: "memory");
            } else if (p == 3) {
                if (nl) asm volatile("s_waitcnt vmcnt(10)" ::: "memory");
                else    asm volatile("s_waitcnt vmcnt(4)"  ::: "memory");
            } else if (p == 5) {
                if (nl) asm volatile("s_waitcnt vmcnt(10)" ::: "memory");
                else    asm volatile("s_waitcnt vmcnt(0)"  ::: "memory");
            } else if (p == 7) {
                if (nl) asm volatile("s_waitcnt vmcnt(10)" ::: "memory");
            }

            // 4. barrier + LDS drain, 5. MFMA cluster, 6. barrier
            __builtin_amdgcn_s_barrier();
            asm volatile("s_waitcnt lgkmcnt(0)" ::: "memory");
            __builtin_amdgcn_s_setprio(1);
            #pragma unroll
            for (int m4 = 0; m4 < 4; ++m4)
                #pragma unroll
                for (int ni = 0; ni < 4; ++ni)
                    acc[ch * 4 + m4][ni] = __builtin_amdgcn_mfma_f32_16x16x32_bf16(
                        afr[m4], bfr[ni], acc[ch * 4 + m4][ni], 0, 0, 0);
            __builtin_amdgcn_s_setprio(0);
            __builtin_amdgcn_s_barrier();
            __builtin_amdgcn_sched_barrier(0);
        }
    }

    // epilogue: C/D layout col = lane&15, row = (lane>>4)*4 + j
    const int crow = (lane >> 4) * 4;
    #pragma unroll
    for (int ni = 0; ni < 4; ++ni) {
        const long long c = n0 + wc * 64 + ni * 16 + la15;
        float bcol = 0.0f;
        if (!BIASROW && bias) bcol = bias[c];
        #pragma unroll
        for (int mi = 0; mi < 8; ++mi) {
            const long long r0 = m0 + wr * 128 + mi * 16 + crow;
            #pragma unroll
            for (int j = 0; j < 4; ++j) {
                float v = acc[mi][ni][j];
                v += BIASROW ? bias[r0 + j] : bcol;
                if (EPI == 1) v = (v > 0.0f) ? (v + 1.0f) : __expf(v);
                const long long idx = bz * cBatch + (r0 + j) * ldc + c;
                if (OUTF32) ((float*)Cout)[idx] = v;
                else        ((bf16*)Cout)[idx]  = (bf16)v;
            }
        }
    }
}

// ---------------- launch ----------------
extern "C" void kernel_launch(void* const* d_in, const int* in_sizes, int n_in,
                              void* d_out, int out_size, void* d_ws, size_t ws_size,
                              hipStream_t stream)
{
    const float* x  = (const float*)d_in[0];
    const float* Wq = (const float*)d_in[1];
    const float* bq = (const float*)d_in[2];
    const float* Wk = (const float*)d_in[3];
    const float* bk = (const float*)d_in[4];
    const float* Wv = (const float*)d_in[5];
    const float* bv = (const float*)d_in[6];
    const float* Wo = (const float*)d_in[7];
    const float* bo = (const float*)d_in[8];
    float* out = (float*)d_out;

    // ws: [0,64M) xb | [64M,128M) Qb (head reused as Wvo+bvo temps, dead before Q)
    //     [128M,144M) KVo | [144M,152M) wqb,wkb,wob,wvT
    // d_out scratch: Kt [0,64M), Vt' [64M,128M) — dead before final write.
    char* ws = (char*)d_ws;
    if (ws_size < (size_t)159383552) return;
    bf16*  xb   = (bf16*)(ws + 0);
    bf16*  Qb   = (bf16*)(ws + 67108864);
    bf16*  Wvo  = (bf16*)(ws + 67108864);            // 2 MB temp in Qb head
    float* bvo  = (float*)(ws + 67108864 + 2097152); // 4 KB temp in Qb
    bf16*  KVo  = (bf16*)(ws + 134217728);
    bf16*  wqb  = (bf16*)(ws + 150994944);
    bf16*  wkb  = wqb + 1048576;
    bf16*  wob  = wkb + 1048576;
    bf16*  wvT  = wob + 1048576;
    bf16*  Kt   = (bf16*)d_out;            // [b][d][s]
    bf16*  Vt   = Kt + NELEM;              // [b][e'][s]

    // 1) converts + folded-weight prep
    cvt_f32_to_bf16<<<4096, 256, 0, stream>>>(x,  xb,  (int)NELEM);
    cvt_f32_to_bf16<<<1024, 256, 0, stream>>>(Wq, wqb, D * D);
    cvt_f32_to_bf16<<<1024, 256, 0, stream>>>(Wk, wkb, D * D);
    cvt_f32_to_bf16<<<1024, 256, 0, stream>>>(Wo, wob, D * D);
    cvt_transpose_1024<<<dim3(16, 16), 256, 0, stream>>>(Wv, wvT);
    bvo_kernel<<<1024, 256, 0, stream>>>(Wo, bv, bvo);

    // 2) Wvo[e'][d] = sum_e Wo[e'][e] Wv[e][d]  (A=wob, B=wvT)
    gemm_bt<128, 128, 2, 2, 0, 0, 0><<<dim3(8, 8, 1), 256, 0, stream>>>(
        wob, wvT, nullptr, Wvo, D, D, D, D, 0, 0, 0);

    // 3) Kt[b][d][s] = elu(Wk x_b^T + bk)+1
    gemm8p<1, 0, 1><<<dim3(16, 4, 8), 512, 0, stream>>>(
        wkb, xb, bk, Kt, D, B * D, S, D, 0, (long long)D, (long long)D * S);

    // 4) Vt'[b][e'][s] = Wvo x_b^T + bvo
    gemm8p<0, 0, 1><<<dim3(16, 4, 8), 512, 0, stream>>>(
        Wvo, xb, bvo, Vt, D, B * D, S, D, 0, (long long)D, (long long)D * S);

    // 5) Qb[(s,b)][d] = elu(x Wq^T + bq)+1   (after Vt': clobbers Wvo/bvo temps)
    gemm8p<1, 0, 0><<<dim3(4, 128, 1), 512, 0, stream>>>(
        xb, wqb, bq, Qb, D, D, D, D, 0, 0, 0);

    // 6) KVo[b][e'][d] = sum_s Vt'[b][e'][s] Kt[b][d][s]
    gemm_bt<128, 128, 2, 2, 0, 0, 0><<<dim3(8, 8, 8), 256, 0, stream>>>(
        Vt, Kt, nullptr, KVo, S, S, D, S,
        (long long)D * S, (long long)D * S, (long long)D * D);

    // 7) out[s,b,e'] = sum_d Qb[(s,b)][d] KVo[b][e'][d] + bo  (fp32)
    gemm8p<0, 1, 0><<<dim3(4, 16, 8), 512, 0, stream>>>(
        Qb, KVo, bo, out, B * D, D, B * D, D,
        (long long)D, (long long)D * D, (long long)D);
}